// Round 10
// baseline (1389.855 us; speedup 1.0000x reference)
//
#include <hip/hip_runtime.h>
#include <math.h>

#define NC    512
#define NG    4
#define NCG   128          // C / G
#define NR    16           // reduced dim
#define NTOPK 384
#define NB    16
#define HW    (112 * 112)  // 12544
#define ALPHA 0.1f
#define EPSC  1e-8f

typedef float f32x4 __attribute__((ext_vector_type(4)));

#define AL(p)    __hip_atomic_load((p), __ATOMIC_RELAXED, __HIP_MEMORY_SCOPE_AGENT)
#define ASR(p,v) __hip_atomic_store((p), (v), __ATOMIC_RELAXED, __HIP_MEMORY_SCOPE_AGENT)

__global__ void init_cnt_kernel(unsigned* cnt) {
  for (int i = threadIdx.x; i < NB * 64; i += 256) cnt[i] = 0u;
}

// One block per (b,c) tile, dispatch order = bc. Tile lives in registers
// across a per-BATCH wait (no grid-wide barrier). x is read once, out
// written once: 822 MB total HBM.
__global__ __launch_bounds__(256, 4) void stream_kernel(
    const float* __restrict__ x, const float* __restrict__ W1,
    const float* __restrict__ bias1, const float* __restrict__ W2,
    const float* __restrict__ bias2, const float* __restrict__ noise_u,
    float* __restrict__ out, unsigned* __restrict__ cnt,
    float* __restrict__ ws_s, float* __restrict__ ws_m) {
  const int bc = (int)blockIdx.x;
  const int b = bc >> 9, c = bc & 511;
  const int t = threadIdx.x;

  __shared__ float comb[2 * NC];
  __shared__ float sc[NC];
  __shared__ float h[NG * NR];
  __shared__ float red_s[4], red_m[4];
  __shared__ int   red_i[4];
  __shared__ float bl_sh;

  // ---- phase 1: NT-load own tile into registers, reduce, post ----
  f32x4 T[13];
  {
    const f32x4* p = reinterpret_cast<const f32x4*>(x + (size_t)bc * HW);
    #pragma unroll
    for (int j = 0; j < 12; ++j)
      T[j] = __builtin_nontemporal_load(&p[t + 256 * j]);
    if (t < 64) T[12] = __builtin_nontemporal_load(&p[3072 + t]);
  }
  float s = 0.f, m = -INFINITY;
  #pragma unroll
  for (int j = 0; j < 12; ++j) {
    f32x4 v = T[j];
    s += (v.x + v.y) + (v.z + v.w);
    m = fmaxf(m, fmaxf(fmaxf(v.x, v.y), fmaxf(v.z, v.w)));
  }
  if (t < 64) {
    f32x4 v = T[12];
    s += (v.x + v.y) + (v.z + v.w);
    m = fmaxf(m, fmaxf(fmaxf(v.x, v.y), fmaxf(v.z, v.w)));
  }
  #pragma unroll
  for (int off = 32; off; off >>= 1) {
    s += __shfl_down(s, off, 64);
    m = fmaxf(m, __shfl_down(m, off, 64));
  }
  if ((t & 63) == 0) { red_s[t >> 6] = s; red_m[t >> 6] = m; }
  __syncthreads();
  if (t == 0) {
    float st = (red_s[0] + red_s[1]) + (red_s[2] + red_s[3]);
    float mt = fmaxf(fmaxf(red_m[0], red_m[1]), fmaxf(red_m[2], red_m[3]));
    ASR(&ws_s[bc], st);
    ASR(&ws_m[bc], mt);
    __hip_atomic_fetch_add(&cnt[b * 64], 1u, __ATOMIC_RELEASE,
                           __HIP_MEMORY_SCOPE_AGENT);
    // ---- phase 2: wait for OWN batch only (siblings are co-dispatched) ----
    while (__hip_atomic_load(&cnt[b * 64], __ATOMIC_ACQUIRE,
                             __HIP_MEMORY_SCOPE_AGENT) < (unsigned)NC)
      __builtin_amdgcn_s_sleep(4);
  }
  __syncthreads();

  // ---- phase 3: mask pipeline for channel c (R5/R8-verified math) ----
  #pragma unroll
  for (int q2 = 0; q2 < 2; ++q2) {
    const int cc = t + q2 * 256;
    comb[cc]      = AL(&ws_s[b * NC + cc]) * (1.0f / (float)HW);
    comb[NC + cc] = AL(&ws_m[b * NC + cc]);
  }
  __syncthreads();
  {  // MLP1: 64 outputs, 4 threads each
    const int pair = t >> 2, sub = t & 3;
    const int g = pair >> 4, r = pair & 15;
    const float* cf = comb + g * (2 * NCG);
    const float* w  = W1 + (size_t)g * (2 * NCG) * NR + r;
    const int i0 = sub * 64;
    float acc = 0.f;
    #pragma unroll 8
    for (int i = 0; i < 64; ++i) acc += cf[i0 + i] * w[(i0 + i) * NR];
    acc += __shfl_down(acc, 2, 4);
    acc += __shfl_down(acc, 1, 4);
    if (sub == 0) h[pair] = fmaxf(acc + bias1[g * NR + r], 0.f);
  }
  __syncthreads();
  #pragma unroll
  for (int cc = 0; cc < 2; ++cc) {  // MLP2: 512 scores
    const int ch = t + cc * 256;
    const int g = ch >> 7, o = ch & 127;
    float acc = bias2[g * NCG + o];
    const float* w  = W2 + (size_t)g * NR * NCG + o;
    const float* hh = h + g * NR;
    #pragma unroll
    for (int r = 0; r < NR; ++r) acc += hh[r] * w[r * NCG];
    sc[ch] = acc;
  }
  __syncthreads();
  {  // exact rank of channel c (stable lowest-index tie-break)
    const float my = sc[c];
    int cnt2 = 0;
    { float v = sc[t];       cnt2 += (v > my) || (v == my && t < c); }
    { float v = sc[t + 256]; cnt2 += (v > my) || (v == my && (t + 256) < c); }
    #pragma unroll
    for (int off = 32; off; off >>= 1) cnt2 += __shfl_down(cnt2, off, 64);
    if ((t & 63) == 0) red_i[t >> 6] = cnt2;
    __syncthreads();
    if (t == 0) {
      const int ct = red_i[0] + red_i[1] + red_i[2] + red_i[3];
      const float hard = (ct < NTOPK) ? 1.f : 0.f;
      const float u = noise_u[b * NC + c];
      const float gum = -logf(-logf(u + EPSC) + EPSC);
      const float soft = 1.f / (1.f + expf(-(my + gum) * 2.0f));  // TAU=0.5
      const float mask = hard * soft;
      bl_sh = mask + (1.f - mask) * ALPHA;
    }
  }
  __syncthreads();

  // ---- phase 4: scale register-resident tile, NT-store ----
  const float bl = bl_sh;
  {
    f32x4* q = reinterpret_cast<f32x4*>(out + (size_t)bc * HW);
    #pragma unroll
    for (int j = 0; j < 12; ++j)
      __builtin_nontemporal_store(T[j] * bl, &q[t + 256 * j]);
    if (t < 64) __builtin_nontemporal_store(T[12] * bl, &q[3072 + t]);
  }
}

extern "C" void kernel_launch(void* const* d_in, const int* in_sizes, int n_in,
                              void* d_out, int out_size, void* d_ws, size_t ws_size,
                              hipStream_t stream) {
  const float* x       = (const float*)d_in[0];
  const float* W1      = (const float*)d_in[1];
  const float* b1      = (const float*)d_in[2];
  const float* W2      = (const float*)d_in[3];
  const float* b2      = (const float*)d_in[4];
  const float* noise_u = (const float*)d_in[5];
  float* out = (float*)d_out;

  unsigned* cnt = (unsigned*)d_ws;                 // 16 counters, 256B apart
  float* ws_s = (float*)((char*)d_ws + 4096);      // [16][512]
  float* ws_m = ws_s + NB * NC;                    // [16][512]

  init_cnt_kernel<<<1, 256, 0, stream>>>(cnt);
  stream_kernel<<<NB * NC, 256, 0, stream>>>(x, W1, b1, W2, b2, noise_u, out,
                                             cnt, ws_s, ws_m);
}

// Round 11
// 659.923 us; speedup vs baseline: 2.1061x; 2.1061x over previous
//
#include <hip/hip_runtime.h>
#include <math.h>

#define NC    512
#define NG    4
#define NCG   128          // C / G
#define NR    16           // reduced dim
#define NTOPK 384
#define NB    16
#define HW    (112 * 112)  // 12544
#define ALPHA 0.1f
#define EPSC  1e-8f

typedef float f32x4 __attribute__((ext_vector_type(4)));

#define AL(p)    __hip_atomic_load((p), __ATOMIC_RELAXED, __HIP_MEMORY_SCOPE_AGENT)
#define ASR(p,v) __hip_atomic_store((p), (v), __ATOMIC_RELAXED, __HIP_MEMORY_SCOPE_AGENT)

__global__ void init_cnt_kernel(unsigned* cnt) {
  for (int i = threadIdx.x; i < NB * 64; i += 256) cnt[i] = 0u;
}

// ---- Kernel 1: pool + (last block per batch) mask compute ----
// 8192 blocks. Each pools one (b,c) tile and posts (sum,max) via agent-scope
// stores + a release-increment of its batch counter. The 512th arriver for a
// batch computes the whole batch's blend vector inline (values deterministic
// regardless of which block does it).
__global__ __launch_bounds__(256) void pool_kernel(
    const float* __restrict__ x, float* __restrict__ ws_s,
    float* __restrict__ ws_m, const float* __restrict__ W1,
    const float* __restrict__ bias1, const float* __restrict__ W2,
    const float* __restrict__ bias2, const float* __restrict__ noise_u,
    float* __restrict__ blend, unsigned* __restrict__ cnt) {
  const int bc = blockIdx.x;
  const int b = bc >> 9;
  const int t = threadIdx.x;

  __shared__ float ss[4], sm[4];
  __shared__ int last_sh;
  __shared__ float comb[2 * NC];
  __shared__ float sc[NC];
  __shared__ float h[NG * NR];

  // pool own tile (NT loads: nothing reuses x through cache)
  const f32x4* p = reinterpret_cast<const f32x4*>(x + (size_t)bc * HW);
  float s = 0.f;
  float m = -INFINITY;
  for (int i = t; i < 3072; i += 1024) {
    f32x4 v0 = __builtin_nontemporal_load(&p[i]);
    f32x4 v1 = __builtin_nontemporal_load(&p[i + 256]);
    f32x4 v2 = __builtin_nontemporal_load(&p[i + 512]);
    f32x4 v3 = __builtin_nontemporal_load(&p[i + 768]);
    s += (v0.x + v0.y) + (v0.z + v0.w);
    s += (v1.x + v1.y) + (v1.z + v1.w);
    s += (v2.x + v2.y) + (v2.z + v2.w);
    s += (v3.x + v3.y) + (v3.z + v3.w);
    m = fmaxf(m, fmaxf(fmaxf(v0.x, v0.y), fmaxf(v0.z, v0.w)));
    m = fmaxf(m, fmaxf(fmaxf(v1.x, v1.y), fmaxf(v1.z, v1.w)));
    m = fmaxf(m, fmaxf(fmaxf(v2.x, v2.y), fmaxf(v2.z, v2.w)));
    m = fmaxf(m, fmaxf(fmaxf(v3.x, v3.y), fmaxf(v3.z, v3.w)));
  }
  if (t < 64) {
    f32x4 v = __builtin_nontemporal_load(&p[3072 + t]);
    s += (v.x + v.y) + (v.z + v.w);
    m = fmaxf(m, fmaxf(fmaxf(v.x, v.y), fmaxf(v.z, v.w)));
  }
  #pragma unroll
  for (int off = 32; off > 0; off >>= 1) {
    s += __shfl_down(s, off, 64);
    m = fmaxf(m, __shfl_down(m, off, 64));
  }
  if ((t & 63) == 0) { ss[t >> 6] = s; sm[t >> 6] = m; }
  __syncthreads();
  if (t == 0) {
    float st = (ss[0] + ss[1]) + (ss[2] + ss[3]);
    float mt = fmaxf(fmaxf(sm[0], sm[1]), fmaxf(sm[2], sm[3]));
    ASR(&ws_s[bc], st);
    ASR(&ws_m[bc], mt);
    unsigned prev = __hip_atomic_fetch_add(&cnt[b * 64], 1u, __ATOMIC_ACQ_REL,
                                           __HIP_MEMORY_SCOPE_AGENT);
    last_sh = (prev == (unsigned)(NC - 1)) ? 1 : 0;
  }
  __syncthreads();
  if (!last_sh) return;

  // ---- we are the 512th arriver for batch b: compute blend[b,:] ----
  #pragma unroll
  for (int q = 0; q < 2; ++q) {
    const int cc = t + q * 256;
    comb[cc]      = AL(&ws_s[b * NC + cc]) * (1.0f / (float)HW);
    comb[NC + cc] = AL(&ws_m[b * NC + cc]);
  }
  __syncthreads();
  {  // MLP1: 64 outputs, 4 threads each (verified R4/R9 code)
    const int pair = t >> 2, sub = t & 3;
    const int g = pair >> 4, r = pair & 15;
    const float* cf = comb + g * (2 * NCG);
    const float* w  = W1 + (size_t)g * (2 * NCG) * NR + r;
    const int i0 = sub * 64;
    float acc = 0.f;
    #pragma unroll 8
    for (int i = 0; i < 64; ++i) acc += cf[i0 + i] * w[(i0 + i) * NR];
    acc += __shfl_down(acc, 2, 4);
    acc += __shfl_down(acc, 1, 4);
    if (sub == 0) h[pair] = fmaxf(acc + bias1[g * NR + r], 0.f);
  }
  __syncthreads();
  #pragma unroll
  for (int cc = 0; cc < 2; ++cc) {  // MLP2: 512 scores
    const int ch = t + cc * 256;
    const int g = ch >> 7, o = ch & 127;
    float acc = bias2[g * NCG + o];
    const float* w  = W2 + (size_t)g * NR * NCG + o;
    const float* hh = h + g * NR;
    #pragma unroll
    for (int r = 0; r < NR; ++r) acc += hh[r] * w[r * NCG];
    sc[ch] = acc;
  }
  __syncthreads();
  // exact rank + blend for all 512 channels (2 per thread; lockstep j-loop
  // reads broadcast from LDS, conflict-free)
  #pragma unroll
  for (int cc = 0; cc < 2; ++cc) {
    const int c = t + cc * 256;
    const float my = sc[c];
    int rk = 0;
    #pragma unroll 8
    for (int j = 0; j < NC; ++j) {
      const float v = sc[j];
      rk += (v > my) || (v == my && j < c);
    }
    const float hard = (rk < NTOPK) ? 1.f : 0.f;
    const float u = noise_u[b * NC + c];
    const float gum = -logf(-logf(u + EPSC) + EPSC);
    const float soft = 1.f / (1.f + expf(-(my + gum) * 2.0f));  // TAU=0.5
    const float mask = hard * soft;
    blend[b * NC + c] = mask + (1.f - mask) * ALPHA;
  }
}

// ---- Kernel 2: pure scale stream, zero prologue ----
// 2048 blocks x 4 tiles. blend[bc] is a uniform scalar load per tile.
__global__ __launch_bounds__(256) void scale_kernel(
    const float* __restrict__ x, const float* __restrict__ blend,
    float* __restrict__ out) {
  const int t = threadIdx.x;
  #pragma unroll
  for (int k = 0; k < 4; ++k) {
    const int bc = (int)blockIdx.x * 4 + k;
    const float sC = blend[bc];
    const f32x4* p = reinterpret_cast<const f32x4*>(x + (size_t)bc * HW);
    f32x4* q = reinterpret_cast<f32x4*>(out + (size_t)bc * HW);
    for (int i = t; i < 3072; i += 1024) {
      f32x4 v0 = __builtin_nontemporal_load(&p[i]);
      f32x4 v1 = __builtin_nontemporal_load(&p[i + 256]);
      f32x4 v2 = __builtin_nontemporal_load(&p[i + 512]);
      f32x4 v3 = __builtin_nontemporal_load(&p[i + 768]);
      v0 *= sC; v1 *= sC; v2 *= sC; v3 *= sC;
      __builtin_nontemporal_store(v0, &q[i]);
      __builtin_nontemporal_store(v1, &q[i + 256]);
      __builtin_nontemporal_store(v2, &q[i + 512]);
      __builtin_nontemporal_store(v3, &q[i + 768]);
    }
    if (t < 64) {
      const int i = 3072 + t;
      f32x4 v = __builtin_nontemporal_load(&p[i]);
      v *= sC;
      __builtin_nontemporal_store(v, &q[i]);
    }
  }
}

extern "C" void kernel_launch(void* const* d_in, const int* in_sizes, int n_in,
                              void* d_out, int out_size, void* d_ws, size_t ws_size,
                              hipStream_t stream) {
  const float* x       = (const float*)d_in[0];
  const float* W1      = (const float*)d_in[1];
  const float* b1      = (const float*)d_in[2];
  const float* W2      = (const float*)d_in[3];
  const float* b2      = (const float*)d_in[4];
  const float* noise_u = (const float*)d_in[5];
  float* out = (float*)d_out;

  unsigned* cnt   = (unsigned*)d_ws;               // 16 counters, 256B apart
  float* ws_s     = (float*)((char*)d_ws + 4096);  // [16][512] raw sums
  float* ws_m     = ws_s + NB * NC;                // [16][512] maxes
  float* ws_blend = ws_m + NB * NC;                // [16][512]

  init_cnt_kernel<<<1, 256, 0, stream>>>(cnt);
  pool_kernel<<<NB * NC, 256, 0, stream>>>(x, ws_s, ws_m, W1, b1, W2, b2,
                                           noise_u, ws_blend, cnt);
  scale_kernel<<<2048, 256, 0, stream>>>(x, ws_blend, out);
}

// Round 12
// 219.648 us; speedup vs baseline: 6.3276x; 3.0045x over previous
//
#include <hip/hip_runtime.h>
#include <math.h>

#define NC    512
#define NG    4
#define NCG   128          // C / G
#define NR    16           // reduced dim
#define NTOPK 384
#define NB    16
#define HW    (112 * 112)  // 12544
#define ALPHA 0.1f
#define EPSC  1e-8f

typedef float f32x4 __attribute__((ext_vector_type(4)));

// ---------------- Kernel 1: per-(b,c) avg + max pooling ----------------
__global__ __launch_bounds__(256) void pool_kernel(
    const float* __restrict__ x, float* __restrict__ avg_out,
    float* __restrict__ max_out) {
  const int bc = blockIdx.x;  // b*C + c
  const f32x4* p = reinterpret_cast<const f32x4*>(x + (size_t)bc * HW);
  float s = 0.f;
  float m = -INFINITY;
  // 3136 = 3*1024 + 64
  for (int i = threadIdx.x; i < 3072; i += 1024) {
    f32x4 v0 = p[i];
    f32x4 v1 = p[i + 256];
    f32x4 v2 = p[i + 512];
    f32x4 v3 = p[i + 768];
    s += (v0.x + v0.y) + (v0.z + v0.w);
    s += (v1.x + v1.y) + (v1.z + v1.w);
    s += (v2.x + v2.y) + (v2.z + v2.w);
    s += (v3.x + v3.y) + (v3.z + v3.w);
    m = fmaxf(m, fmaxf(fmaxf(v0.x, v0.y), fmaxf(v0.z, v0.w)));
    m = fmaxf(m, fmaxf(fmaxf(v1.x, v1.y), fmaxf(v1.z, v1.w)));
    m = fmaxf(m, fmaxf(fmaxf(v2.x, v2.y), fmaxf(v2.z, v2.w)));
    m = fmaxf(m, fmaxf(fmaxf(v3.x, v3.y), fmaxf(v3.z, v3.w)));
  }
  if (threadIdx.x < 64) {
    f32x4 v = p[3072 + threadIdx.x];
    s += (v.x + v.y) + (v.z + v.w);
    m = fmaxf(m, fmaxf(fmaxf(v.x, v.y), fmaxf(v.z, v.w)));
  }
  #pragma unroll
  for (int off = 32; off > 0; off >>= 1) {
    s += __shfl_down(s, off, 64);
    m = fmaxf(m, __shfl_down(m, off, 64));
  }
  __shared__ float ss[4], sm[4];
  const int wave = threadIdx.x >> 6;
  const int lane = threadIdx.x & 63;
  if (lane == 0) { ss[wave] = s; sm[wave] = m; }
  __syncthreads();
  if (threadIdx.x == 0) {
    float st = (ss[0] + ss[1]) + (ss[2] + ss[3]);
    float mt = fmaxf(fmaxf(sm[0], sm[1]), fmaxf(sm[2], sm[3]));
    avg_out[bc] = st / (float)HW;
    max_out[bc] = mt;
  }
}

// -------- Kernel 2: fused mask-compute + scale --------
// 2048 blocks x 256 thr. Reversed block rb owns 4 channels of one batch:
// b = rb>>7, c0 = (rb&127)*4. Prologue recomputes the per-batch mask
// pipeline (deterministic, identical across the 128 blocks of a batch),
// keeps 4 blend values in LDS, then streams 4 tiles LIFO.
__global__ __launch_bounds__(256) void fused_kernel(
    const float* __restrict__ x, const float* __restrict__ avg,
    const float* __restrict__ mx, const float* __restrict__ W1,
    const float* __restrict__ b1, const float* __restrict__ W2,
    const float* __restrict__ b2, const float* __restrict__ noise_u,
    float* __restrict__ out) {
  const int rb = 2047 - (int)blockIdx.x;  // reversed: tail blocks first
  const int b  = rb >> 7;                 // 128 blocks per batch
  const int c0 = (rb & 127) * 4;          // this block's 4 channels
  const int t  = threadIdx.x;

  __shared__ float comb[2 * NC];   // [avg(512) | max(512)]
  __shared__ float h[NG * NR];     // 64
  __shared__ float sc[NC];         // 512
  __shared__ float blend_loc[4];

  // ---- load pooled features for batch b (coalesced) ----
  {
    const float* pa = avg + b * NC;
    const float* pm = mx  + b * NC;
    comb[t]             = pa[t];
    comb[t + 256]       = pa[t + 256];
    comb[512 + t]       = pm[t];
    comb[512 + t + 256] = pm[t + 256];
  }
  __syncthreads();

  // ---- MLP1: 64 outputs, 4 threads each (64 MACs + shfl4 reduce) ----
  {
    const int pair = t >> 2, sub = t & 3;   // pair in [0,64)
    const int g = pair >> 4, r = pair & 15;
    const float* cf = comb + g * (2 * NCG);        // 256 inputs for group g
    const float* w  = W1 + (size_t)g * (2 * NCG) * NR + r;  // stride NR
    const int i0 = sub * 64;
    float acc = 0.f;
    #pragma unroll 8
    for (int i = 0; i < 64; ++i) acc += cf[i0 + i] * w[(i0 + i) * NR];
    acc += __shfl_down(acc, 2, 4);
    acc += __shfl_down(acc, 1, 4);
    if (sub == 0) h[pair] = fmaxf(acc + b1[g * NR + r], 0.f);
  }
  __syncthreads();

  // ---- MLP2: 512 scores, 2 per thread ----
  #pragma unroll
  for (int cc = 0; cc < 2; ++cc) {
    const int c = t + cc * 256;
    const int g = c >> 7, o = c & 127;
    float acc = b2[g * NCG + o];
    const float* w  = W2 + (size_t)g * NR * NCG + o;  // stride NCG
    const float* hh = h + g * NR;
    #pragma unroll
    for (int r = 0; r < NR; ++r) acc += hh[r] * w[r * NCG];
    sc[c] = acc;
  }
  __syncthreads();

  // ---- exact rank-count for our 4 channels (64 threads per channel) ----
  {
    const int ci = t >> 6, sub = t & 63;
    const int c = c0 + ci;
    const float my = sc[c];
    int cnt = 0;
    const int j0 = sub * 8;
    #pragma unroll
    for (int jj = 0; jj < 8; ++jj) {
      const int j = j0 + jj;
      const float v = sc[j];
      cnt += (v > my) || (v == my && j < c);
    }
    #pragma unroll
    for (int off = 32; off > 0; off >>= 1) cnt += __shfl_down(cnt, off, 64);
    if (sub == 0) {
      const float hard = (cnt < NTOPK) ? 1.f : 0.f;
      const float u = noise_u[b * NC + c];
      const float gum = -logf(-logf(u + EPSC) + EPSC);
      const float soft = 1.f / (1.f + expf(-(my + gum) * 2.0f));  // TAU=0.5
      const float mask = hard * soft;
      blend_loc[ci] = mask + (1.f - mask) * ALPHA;
    }
  }
  __syncthreads();

  // ---- scale the 4 owned tiles, LIFO order (descending bc) ----
  for (int k = 3; k >= 0; --k) {
    const int bc = (b * NC) + c0 + k;
    const float s = blend_loc[k];
    const f32x4* p = reinterpret_cast<const f32x4*>(x + (size_t)bc * HW);
    f32x4* q = reinterpret_cast<f32x4*>(out + (size_t)bc * HW);
    for (int i = t; i < 3072; i += 1024) {
      f32x4 v0 = p[i];
      f32x4 v1 = p[i + 256];
      f32x4 v2 = p[i + 512];
      f32x4 v3 = p[i + 768];
      v0 *= s; v1 *= s; v2 *= s; v3 *= s;
      __builtin_nontemporal_store(v0, &q[i]);
      __builtin_nontemporal_store(v1, &q[i + 256]);
      __builtin_nontemporal_store(v2, &q[i + 512]);
      __builtin_nontemporal_store(v3, &q[i + 768]);
    }
    if (t < 64) {
      const int i = 3072 + t;
      f32x4 v = p[i];
      v *= s;
      __builtin_nontemporal_store(v, &q[i]);
    }
  }
}

extern "C" void kernel_launch(void* const* d_in, const int* in_sizes, int n_in,
                              void* d_out, int out_size, void* d_ws, size_t ws_size,
                              hipStream_t stream) {
  const float* x       = (const float*)d_in[0];
  const float* W1      = (const float*)d_in[1];
  const float* b1      = (const float*)d_in[2];
  const float* W2      = (const float*)d_in[3];
  const float* b2      = (const float*)d_in[4];
  const float* noise_u = (const float*)d_in[5];
  float* out = (float*)d_out;

  float* ws_avg = (float*)d_ws;        // B*C floats
  float* ws_max = ws_avg + NB * NC;    // B*C floats

  pool_kernel<<<NB * NC, 256, 0, stream>>>(x, ws_avg, ws_max);
  fused_kernel<<<2048, 256, 0, stream>>>(x, ws_avg, ws_max, W1, b1, W2, b2,
                                         noise_u, out);
}